// Round 1
// baseline (572.871 us; speedup 1.0000x reference)
//
#include <hip/hip_runtime.h>

// LengthAdaptor: B=16, T=512, C_IN=512, C_HID=256, C_EMB=384, K=5, MAX_DUR=8
// Outputs (concat, f32): x_up [16,4096,512] | ldp [16,512] | emb_up [16,4096,384]

constexpr int Bn = 16, Tn = 512, CIN1 = 512, CHID = 256, CEMB = 384, MAXMEL = 4096;
#define LRELU 0.3f
#define EPSV 1e-5f

// ---------------------------------------------------------------------------
// Kernel 1: per-batch inclusive scan of durations, scatter frame index per
// output position, -1 for invalid tail. One block per batch, 512 threads.
// ---------------------------------------------------------------------------
__global__ __launch_bounds__(512) void build_idx_kernel(const int* __restrict__ dur,
                                                        int* __restrict__ idx) {
  __shared__ int cum[Tn];
  const int b = blockIdx.x, t = threadIdx.x;
  const int d = dur[b * Tn + t];
  cum[t] = d;
  __syncthreads();
  // Hillis-Steele inclusive scan (read, sync, write, sync)
  for (int off = 1; off < Tn; off <<= 1) {
    int v = (t >= off) ? cum[t - off] : 0;
    __syncthreads();
    cum[t] += v;
    __syncthreads();
  }
  const int end = cum[t];
  for (int p = end - d; p < end; ++p) idx[b * MAXMEL + p] = t;  // d <= 7 writes
  const int total = cum[Tn - 1];                                 // <= 3584 < 4096
  for (int p = total + t; p < MAXMEL; p += Tn) idx[b * MAXMEL + p] = -1;
}

// ---------------------------------------------------------------------------
// Kernel 2: gather rows for x_up and emb_up. One block per (b, p).
// tid<128: x row as float4 (512 f32); tid in [128,224): emb row (384 f32).
// idx==-1 -> zeros (position past total duration).
// ---------------------------------------------------------------------------
__global__ __launch_bounds__(256) void gather_kernel(const float* __restrict__ x,
                                                     const float* __restrict__ emb,
                                                     const int* __restrict__ idx,
                                                     float* __restrict__ x_up,
                                                     float* __restrict__ emb_up) {
  const int bp = blockIdx.x;          // b*4096 + p
  const int b = bp >> 12;
  const int t = idx[bp];              // broadcast load
  const int tid = threadIdx.x;
  const float4 z = make_float4(0.f, 0.f, 0.f, 0.f);
  if (tid < 128) {
    float4 v = z;
    if (t >= 0) v = ((const float4*)(x + ((size_t)(b * Tn + t)) * CIN1))[tid];
    ((float4*)(x_up + (size_t)bp * CIN1))[tid] = v;
  } else if (tid < 128 + 96) {
    const int i = tid - 128;
    float4 v = z;
    if (t >= 0) v = ((const float4*)(emb + ((size_t)(b * Tn + t)) * CEMB))[i];
    ((float4*)(emb_up + (size_t)bp * CEMB))[i] = v;
  }
}

// ---------------------------------------------------------------------------
// Kernel 3/4: conv1d(K=5, same-pad) + bias + leaky_relu + layernorm,
// optionally fused final linear (256->1) + mask.
// Block = 256 threads (1 thread per out-channel), TT=16 timesteps per block.
// Stages TT+4 input rows in LDS; K-loop processes 4 c_in per iteration:
//   20 ds_read_b128 broadcasts + 20 coalesced weight dwords + 320 FMA.
// ---------------------------------------------------------------------------
template <int CIN, bool FINAL>
__global__ __launch_bounds__(256) void conv_ln_kernel(
    const float* __restrict__ in,     // [B*T, CIN]
    const float* __restrict__ w,      // [5, CIN, 256]
    const float* __restrict__ bias,   // [256]
    const float* __restrict__ g, const float* __restrict__ be,  // LN gamma/beta
    float* __restrict__ hout,         // [B*T, 256] if !FINAL
    const float* __restrict__ lw, const float* __restrict__ lb,
    const unsigned char* __restrict__ mask,
    float* __restrict__ ldp)          // [B*T] if FINAL
{
  constexpr int TT = 16, ROWS = TT + 4;
  __shared__ float sx[ROWS * CIN];    // conv1: 40 KB, conv2: 20 KB
  __shared__ float sh[TT * 257];      // 16.1 KB, +1 pad vs 256 stride
  __shared__ float sp1[TT * 16];
  __shared__ float sp2[TT * 16];
  __shared__ float smu[TT], srs[TT];

  const int blk = blockIdx.x;         // 512 blocks = 16 batches * 32 tiles
  const int b = blk >> 5;
  const int t0 = (blk & 31) * TT;
  const int c = threadIdx.x;          // out-channel

  // stage input rows t0-2 .. t0+17 (zero-pad outside [0,T))
  for (int r = 0; r < ROWS; ++r) {
    const int t = t0 + r - 2;
    const bool ok = (unsigned)t < (unsigned)Tn;
    const float* src = in + ((size_t)(b * Tn + t)) * CIN;
#pragma unroll
    for (int i = 0; i < CIN / 256; ++i)
      sx[r * CIN + i * 256 + c] = ok ? src[i * 256 + c] : 0.f;
  }
  __syncthreads();

  float acc[TT];
#pragma unroll
  for (int tt = 0; tt < TT; ++tt) acc[tt] = 0.f;

  for (int ci = 0; ci < CIN; ci += 4) {
    float4 xv[ROWS];
#pragma unroll
    for (int r = 0; r < ROWS; ++r)
      xv[r] = *(const float4*)&sx[r * CIN + ci];   // broadcast b128, no conflict
#pragma unroll
    for (int k = 0; k < 5; ++k) {
      const float* wp = w + ((size_t)k * CIN + ci) * CHID + c;
      const float w0 = wp[0], w1 = wp[CHID], w2 = wp[2 * CHID], w3 = wp[3 * CHID];
#pragma unroll
      for (int tt = 0; tt < TT; ++tt) {
        const float4 xc = xv[tt + k];
        acc[tt] += xc.x * w0;
        acc[tt] += xc.y * w1;
        acc[tt] += xc.z * w2;
        acc[tt] += xc.w * w3;
      }
    }
  }

  // bias + leaky relu, stash for LN reduction
  const float bi = bias[c];
#pragma unroll
  for (int tt = 0; tt < TT; ++tt) {
    float v = acc[tt] + bi;
    v = (v > 0.f) ? v : LRELU * v;
    acc[tt] = v;
    sh[tt * 257 + c] = v;
  }
  __syncthreads();

  // LN stats: 16 segments of 16 channels per timestep
  {
    const int tt = c >> 4, sg = c & 15;
    float s = 0.f, s2 = 0.f;
#pragma unroll
    for (int j = 0; j < 16; ++j) {
      const float v = sh[tt * 257 + sg * 16 + j];
      s += v;
      s2 += v * v;
    }
    sp1[tt * 16 + sg] = s;
    sp2[tt * 16 + sg] = s2;
  }
  __syncthreads();
  if (c < TT) {
    float s = 0.f, s2 = 0.f;
#pragma unroll
    for (int j = 0; j < 16; ++j) { s += sp1[c * 16 + j]; s2 += sp2[c * 16 + j]; }
    const float mu = s * (1.f / CHID);
    const float var = s2 * (1.f / CHID) - mu * mu;
    smu[c] = mu;
    srs[c] = rsqrtf(var + EPSV);
  }
  __syncthreads();

  const float gg = g[c], bb = be[c];
  if (!FINAL) {
#pragma unroll
    for (int tt = 0; tt < TT; ++tt) {
      const float h = (acc[tt] - smu[tt]) * srs[tt] * gg + bb;
      hout[((size_t)(b * Tn + t0 + tt)) * CHID + c] = h;
    }
  } else {
    const float lwc = lw[c];
#pragma unroll
    for (int tt = 0; tt < TT; ++tt) {
      const float h = (acc[tt] - smu[tt]) * srs[tt] * gg + bb;
      sh[tt * 257 + c] = h * lwc;
    }
    __syncthreads();
    {
      const int tt = c >> 4, sg = c & 15;
      float s = 0.f;
#pragma unroll
      for (int j = 0; j < 16; ++j) s += sh[tt * 257 + sg * 16 + j];
      sp1[tt * 16 + sg] = s;
    }
    __syncthreads();
    if (c < TT) {
      float s = 0.f;
#pragma unroll
      for (int j = 0; j < 16; ++j) s += sp1[c * 16 + j];
      float v = s + lb[0];
      const int t = t0 + c;
      if (mask[b * Tn + t]) v = 0.f;   // src_mask all-false in this bench
      ldp[b * Tn + t] = v;
    }
  }
}

// ---------------------------------------------------------------------------
extern "C" void kernel_launch(void* const* d_in, const int* in_sizes, int n_in,
                              void* d_out, int out_size, void* d_ws, size_t ws_size,
                              hipStream_t stream) {
  const float* x      = (const float*)d_in[0];   // [16,512,512]
  const float* x_res  = (const float*)d_in[1];   // [16,512,512]
  const int*   dur    = (const int*)d_in[2];     // [16,512]
  const float* emb    = (const float*)d_in[3];   // [16,512,384]
  const unsigned char* mask = (const unsigned char*)d_in[4];  // [16,512] bool (all false)
  const float* c1w = (const float*)d_in[5];      // [5,512,256]
  const float* c1b = (const float*)d_in[6];
  const float* g1  = (const float*)d_in[7];
  const float* b1  = (const float*)d_in[8];
  const float* c2w = (const float*)d_in[9];      // [5,256,256]
  const float* c2b = (const float*)d_in[10];
  const float* g2  = (const float*)d_in[11];
  const float* b2  = (const float*)d_in[12];
  const float* lw  = (const float*)d_in[13];     // [256,1]
  const float* lb  = (const float*)d_in[14];     // [1]

  float* x_up   = (float*)d_out;                           // 16*4096*512
  float* ldp    = x_up + (size_t)Bn * MAXMEL * CIN1;       // 16*512
  float* emb_up = ldp + (size_t)Bn * Tn;                   // 16*4096*384

  int*   idx = (int*)d_ws;                                           // 256 KB
  float* h1  = (float*)((char*)d_ws + (size_t)Bn * MAXMEL * sizeof(int));  // 8 MB

  build_idx_kernel<<<Bn, Tn, 0, stream>>>(dur, idx);
  gather_kernel<<<Bn * MAXMEL, 256, 0, stream>>>(x, emb, idx, x_up, emb_up);
  conv_ln_kernel<CIN1, false><<<512, 256, 0, stream>>>(
      x_res, c1w, c1b, g1, b1, h1, nullptr, nullptr, nullptr, nullptr);
  conv_ln_kernel<CHID, true><<<512, 256, 0, stream>>>(
      h1, c2w, c2b, g2, b2, nullptr, lw, lb, mask, ldp);
}

// Round 2
// 488.275 us; speedup vs baseline: 1.1733x; 1.1733x over previous
//
#include <hip/hip_runtime.h>

// LengthAdaptor: B=16, T=512, C_IN=512, C_HID=256, C_EMB=384, K=5, MAX_DUR=8
// Outputs (concat, f32): x_up [16,4096,512] | ldp [16,512] | emb_up [16,4096,384]
//
// Convs as bf16 MFMA implicit GEMM with hi/lo split precision:
//   A = Ah + Al, B = Bh + Bl;  D ≈ Ah*Bh + Al*Bh + Ah*Bl  (fp32-grade)
// conv kernel: Mtile=64, Ntile=128, Ksplit=2 -> grid(128,2,2), 4 waves/block,
// per-wave 32x64 (8 subtiles 16x16, acc 32 VGPR). A in LDS (stride 72 = 2-way
// bank alias, free); B direct from L2 (pre-transposed [k][co][ci] bf16).

constexpr int Bn = 16, Tn = 512, CIN1 = 512, CHID = 256, CEMB = 384, MAXMEL = 4096;
constexpr int NROWS = Bn * Tn;  // 8192 GEMM rows
#define LRELU 0.3f
#define EPSV 1e-5f

typedef __attribute__((ext_vector_type(8))) short bf16x8;
typedef __attribute__((ext_vector_type(4))) float f32x4;
typedef unsigned short ushort_t;

static __device__ __forceinline__ ushort_t f2bf(float f) {
  unsigned u = __builtin_bit_cast(unsigned, f);
  unsigned r = (u + 0x7fffu + ((u >> 16) & 1u)) >> 16;  // RNE
  return (ushort_t)r;
}
static __device__ __forceinline__ float bf2f(ushort_t h) {
  unsigned u = ((unsigned)h) << 16;
  return __builtin_bit_cast(float, u);
}

// ---------------------------------------------------------------------------
// Weight prep: w [5][CI][256] f32 -> wT_hi/wT_lo [5][256][CI] bf16 (transpose)
// ---------------------------------------------------------------------------
__global__ __launch_bounds__(256) void wprep_kernel(const float* __restrict__ w,
                                                    ushort_t* __restrict__ hi,
                                                    ushort_t* __restrict__ lo,
                                                    int CI) {
  __shared__ float tle[32][33];
  const int k = blockIdx.z, ci0 = blockIdx.x * 32, co0 = blockIdx.y * 32;
  const int tx = threadIdx.x & 31, ty = threadIdx.x >> 5;
#pragma unroll
  for (int r = 0; r < 4; ++r) {
    const int ci = ty + 8 * r;
    tle[ci][tx] = w[((size_t)(k * CI + ci0 + ci)) * 256 + co0 + tx];
  }
  __syncthreads();
#pragma unroll
  for (int r = 0; r < 4; ++r) {
    const int co = ty + 8 * r;
    const float v = tle[tx][co];
    const ushort_t h = f2bf(v);
    const size_t o = ((size_t)(k * 256 + co0 + co)) * CI + ci0 + tx;
    hi[o] = h;
    lo[o] = f2bf(v - bf2f(h));
  }
}

// ---------------------------------------------------------------------------
// Conv MFMA kernel. Template: CI (512 or 256), F32IN (x_res f32 vs h1 bf16).
// grid (mt=128, ns=2, ks=2), block 256 = 4 waves (2 mh x 2 nh).
// Writes partial sums (no bias) to part[ks][8192][256] f32.
// ---------------------------------------------------------------------------
template <int CI, bool F32IN>
__global__ __launch_bounds__(256) void conv_mfma_kernel(
    const float* __restrict__ xin,        // F32IN: [8192][CI]
    const ushort_t* __restrict__ inhi,    // !F32IN: [8192][CI] bf16 hi
    const ushort_t* __restrict__ inlo,
    const ushort_t* __restrict__ wThi,    // [5][256][CI]
    const ushort_t* __restrict__ wTlo,
    float* __restrict__ part) {           // [2][8192][256]
  constexpr int CIH = CI / 2;             // K-split half
  constexpr int NCHUNK = CIH / 64;
  constexpr int LDSTRIDE = 72;            // 64 + 8 pad: 2-way bank alias (free)
  __shared__ ushort_t sAhi[68 * LDSTRIDE];
  __shared__ ushort_t sAlo[68 * LDSTRIDE];

  const int mt = blockIdx.x, ns = blockIdx.y, ks = blockIdx.z;
  const int b = mt >> 3, t0 = (mt & 7) * 64;
  const int tid = threadIdx.x;
  const int l = tid & 63, w = tid >> 6;
  const int mh = w >> 1, nh = w & 1;
  const int m0w = mh * 32;
  const int lm = l & 15, lq = l >> 4;

  f32x4 acc[2][4];
#pragma unroll
  for (int im = 0; im < 2; ++im)
#pragma unroll
    for (int jn = 0; jn < 4; ++jn) acc[im][jn] = (f32x4){0.f, 0.f, 0.f, 0.f};

  // per-lane B pointers (layout: n = lane&15, k = (lane>>4)*8 + j contiguous)
  const int coBase = ns * 128 + nh * 64 + lm;
  const ushort_t* pBh[4];
  const ushort_t* pBl[4];
#pragma unroll
  for (int jn = 0; jn < 4; ++jn) {
    const size_t o = (size_t)(coBase + jn * 16) * CI + ks * CIH + lq * 8;
    pBh[jn] = wThi + o;
    pBl[jn] = wTlo + o;
  }
  const int rowBase = m0w + lm;   // A layout: m = lane&15
  const int colBase = lq * 8;     //           k = (lane>>4)*8 + j

#pragma unroll 1
  for (int chunk = 0; chunk < NCHUNK; ++chunk) {
    // ---- stage 68 rows x 64 ci of A (hi/lo bf16) ----
    {
      const int cibase = ks * CIH + chunk * 64;
#pragma unroll 1
      for (int i = 0; i < 17; ++i) {              // 17*256 = 4352 = 68*64
        const int e = i * 256 + tid;
        const int r = e >> 6, c = e & 63;
        const int t = t0 - 2 + r;
        ushort_t hv = 0, lv = 0;
        if ((unsigned)t < (unsigned)Tn) {
          const size_t src = (size_t)(b * Tn + t) * CI + cibase + c;
          if (F32IN) {
            const float v = xin[src];
            hv = f2bf(v);
            lv = f2bf(v - bf2f(hv));
          } else {
            hv = inhi[src];
            lv = inlo[src];
          }
        }
        sAhi[r * LDSTRIDE + c] = hv;
        sAlo[r * LDSTRIDE + c] = lv;
      }
    }
    __syncthreads();

#pragma unroll 1
    for (int ksh = 0; ksh < 5; ++ksh) {
#pragma unroll
      for (int kk = 0; kk < 2; ++kk) {
        bf16x8 a_h[2], a_l[2];
#pragma unroll
        for (int im = 0; im < 2; ++im) {
          const int ad = (rowBase + im * 16 + ksh) * LDSTRIDE + kk * 32 + colBase;
          a_h[im] = *(const bf16x8*)&sAhi[ad];
          a_l[im] = *(const bf16x8*)&sAlo[ad];
        }
        const int boff = ksh * (256 * CI) + chunk * 64 + kk * 32;
#pragma unroll
        for (int jn = 0; jn < 4; ++jn) {
          const bf16x8 bh = *(const bf16x8*)(pBh[jn] + boff);
          const bf16x8 bl = *(const bf16x8*)(pBl[jn] + boff);
#pragma unroll
          for (int im = 0; im < 2; ++im) {
            acc[im][jn] = __builtin_amdgcn_mfma_f32_16x16x32_bf16(a_h[im], bh, acc[im][jn], 0, 0, 0);
            acc[im][jn] = __builtin_amdgcn_mfma_f32_16x16x32_bf16(a_l[im], bh, acc[im][jn], 0, 0, 0);
            acc[im][jn] = __builtin_amdgcn_mfma_f32_16x16x32_bf16(a_h[im], bl, acc[im][jn], 0, 0, 0);
          }
        }
      }
    }
    __syncthreads();
  }

  // ---- write partials; D layout: col = lane&15, row = (lane>>4)*4 + reg ----
  float* pOut = part + (size_t)ks * NROWS * 256;
#pragma unroll
  for (int im = 0; im < 2; ++im)
#pragma unroll
    for (int jn = 0; jn < 4; ++jn) {
      const int col = coBase + jn * 16;
#pragma unroll
      for (int reg = 0; reg < 4; ++reg) {
        const int grow = b * Tn + t0 + m0w + im * 16 + lq * 4 + reg;
        pOut[(size_t)grow * 256 + col] = acc[im][jn][reg];
      }
    }
}

// ---------------------------------------------------------------------------
// Reduce Ksplit + bias + leaky-relu + LayerNorm. One wave per row.
// FINAL=false: emit h1 as bf16 hi/lo. FINAL=true: fused linear -> ldp.
// ---------------------------------------------------------------------------
template <bool FINAL>
__global__ __launch_bounds__(256) void ln_kernel(
    const float* __restrict__ part0, const float* __restrict__ part1,
    const float* __restrict__ bias, const float* __restrict__ g,
    const float* __restrict__ be, ushort_t* __restrict__ h1hi,
    ushort_t* __restrict__ h1lo, const float* __restrict__ lw,
    const float* __restrict__ lb, const unsigned char* __restrict__ mask,
    float* __restrict__ ldp) {
  const int row = blockIdx.x * 4 + (threadIdx.x >> 6);
  const int l = threadIdx.x & 63;
  const float4 p0 = ((const float4*)part0)[row * 64 + l];
  const float4 p1 = ((const float4*)part1)[row * 64 + l];
  const float4 bi = ((const float4*)bias)[l];
  float v0 = p0.x + p1.x + bi.x, v1 = p0.y + p1.y + bi.y;
  float v2 = p0.z + p1.z + bi.z, v3 = p0.w + p1.w + bi.w;
  v0 = (v0 > 0.f) ? v0 : LRELU * v0;
  v1 = (v1 > 0.f) ? v1 : LRELU * v1;
  v2 = (v2 > 0.f) ? v2 : LRELU * v2;
  v3 = (v3 > 0.f) ? v3 : LRELU * v3;
  float s = v0 + v1 + v2 + v3;
  float s2 = v0 * v0 + v1 * v1 + v2 * v2 + v3 * v3;
#pragma unroll
  for (int off = 32; off >= 1; off >>= 1) {
    s += __shfl_xor(s, off);
    s2 += __shfl_xor(s2, off);
  }
  const float mu = s * (1.f / 256.f);
  const float var = s2 * (1.f / 256.f) - mu * mu;
  const float rs = rsqrtf(var + EPSV);
  const float4 gg = ((const float4*)g)[l];
  const float4 bb = ((const float4*)be)[l];
  const float h0 = (v0 - mu) * rs * gg.x + bb.x;
  const float h1 = (v1 - mu) * rs * gg.y + bb.y;
  const float h2 = (v2 - mu) * rs * gg.z + bb.z;
  const float h3 = (v3 - mu) * rs * gg.w + bb.w;
  if (!FINAL) {
    ushort4 uh, ul;
    uh.x = f2bf(h0); ul.x = f2bf(h0 - bf2f(uh.x));
    uh.y = f2bf(h1); ul.y = f2bf(h1 - bf2f(uh.y));
    uh.z = f2bf(h2); ul.z = f2bf(h2 - bf2f(uh.z));
    uh.w = f2bf(h3); ul.w = f2bf(h3 - bf2f(uh.w));
    ((ushort4*)h1hi)[row * 64 + l] = uh;
    ((ushort4*)h1lo)[row * 64 + l] = ul;
  } else {
    const float4 lv = ((const float4*)lw)[l];
    float d = h0 * lv.x + h1 * lv.y + h2 * lv.z + h3 * lv.w;
#pragma unroll
    for (int off = 32; off >= 1; off >>= 1) d += __shfl_xor(d, off);
    if (l == 0) {
      float val = d + lb[0];
      if (mask[row]) val = 0.f;
      ldp[row] = val;
    }
  }
}

// ---------------------------------------------------------------------------
// Length regulation
// ---------------------------------------------------------------------------
__global__ __launch_bounds__(512) void build_idx_kernel(const int* __restrict__ dur,
                                                        int* __restrict__ idx) {
  __shared__ int cum[Tn];
  const int b = blockIdx.x, t = threadIdx.x;
  const int d = dur[b * Tn + t];
  cum[t] = d;
  __syncthreads();
  for (int off = 1; off < Tn; off <<= 1) {
    int v = (t >= off) ? cum[t - off] : 0;
    __syncthreads();
    cum[t] += v;
    __syncthreads();
  }
  const int end = cum[t];
  for (int p = end - d; p < end; ++p) idx[b * MAXMEL + p] = t;
  const int total = cum[Tn - 1];
  for (int p = total + t; p < MAXMEL; p += Tn) idx[b * MAXMEL + p] = -1;
}

__global__ __launch_bounds__(256) void gather_kernel(const float* __restrict__ x,
                                                     const float* __restrict__ emb,
                                                     const int* __restrict__ idx,
                                                     float* __restrict__ x_up,
                                                     float* __restrict__ emb_up) {
  const float4* x4 = (const float4*)x;
  const float4* e4 = (const float4*)emb;
  float4* xu4 = (float4*)x_up;
  float4* eu4 = (float4*)emb_up;
  const int tid0 = blockIdx.x * 256 + threadIdx.x;
  const int stride = gridDim.x * 256;
  const float4 z = make_float4(0.f, 0.f, 0.f, 0.f);
  for (int u = tid0; u < Bn * MAXMEL * 128; u += stride) {
    const int bp = u >> 7, i = u & 127;
    const int t = idx[bp];
    const int b = bp >> 12;
    xu4[u] = (t >= 0) ? x4[((b << 9) + t) * 128 + i] : z;
  }
  for (int u = tid0; u < Bn * MAXMEL * 96; u += stride) {
    const int bp = u / 96, i = u - bp * 96;
    const int t = idx[bp];
    const int b = bp >> 12;
    eu4[u] = (t >= 0) ? e4[((b << 9) + t) * 96 + i] : z;
  }
}

// ---------------------------------------------------------------------------
extern "C" void kernel_launch(void* const* d_in, const int* in_sizes, int n_in,
                              void* d_out, int out_size, void* d_ws, size_t ws_size,
                              hipStream_t stream) {
  const float* x     = (const float*)d_in[0];
  const float* x_res = (const float*)d_in[1];
  const int*   dur   = (const int*)d_in[2];
  const float* emb   = (const float*)d_in[3];
  const unsigned char* mask = (const unsigned char*)d_in[4];
  const float* c1w = (const float*)d_in[5];
  const float* c1b = (const float*)d_in[6];
  const float* g1  = (const float*)d_in[7];
  const float* b1  = (const float*)d_in[8];
  const float* c2w = (const float*)d_in[9];
  const float* c2b = (const float*)d_in[10];
  const float* g2  = (const float*)d_in[11];
  const float* b2  = (const float*)d_in[12];
  const float* lw  = (const float*)d_in[13];
  const float* lb  = (const float*)d_in[14];

  float* x_up   = (float*)d_out;
  float* ldp    = x_up + (size_t)Bn * MAXMEL * CIN1;
  float* emb_up = ldp + (size_t)Bn * Tn;

  // Scratch inside emb_up region (100.7 MB) — overwritten last by gather.
  float* part0 = emb_up;                             // 8 MB
  float* part1 = part0 + (size_t)NROWS * 256;        // 8 MB
  ushort_t* w1hi = (ushort_t*)(part1 + (size_t)NROWS * 256);
  ushort_t* w1lo = w1hi + (size_t)5 * 256 * 512;
  ushort_t* w2hi = w1lo + (size_t)5 * 256 * 512;
  ushort_t* w2lo = w2hi + (size_t)5 * 256 * 256;

  // ws: idx (256 KB) + h1 hi/lo (8 MB) — same footprint as round 1.
  int* idx = (int*)d_ws;
  ushort_t* h1hi = (ushort_t*)((char*)d_ws + (size_t)Bn * MAXMEL * sizeof(int));
  ushort_t* h1lo = h1hi + (size_t)NROWS * 256;

  wprep_kernel<<<dim3(16, 8, 5), 256, 0, stream>>>(c1w, w1hi, w1lo, 512);
  wprep_kernel<<<dim3(8, 8, 5), 256, 0, stream>>>(c2w, w2hi, w2lo, 256);
  conv_mfma_kernel<512, true><<<dim3(128, 2, 2), 256, 0, stream>>>(
      x_res, nullptr, nullptr, w1hi, w1lo, part0);
  ln_kernel<false><<<NROWS / 4, 256, 0, stream>>>(
      part0, part1, c1b, g1, b1, h1hi, h1lo, nullptr, nullptr, nullptr, nullptr);
  conv_mfma_kernel<256, false><<<dim3(128, 2, 2), 256, 0, stream>>>(
      nullptr, h1hi, h1lo, w2hi, w2lo, part0);
  ln_kernel<true><<<NROWS / 4, 256, 0, stream>>>(
      part0, part1, c2b, g2, b2, nullptr, nullptr, lw, lb, mask, ldp);
  build_idx_kernel<<<Bn, Tn, 0, stream>>>(dur, idx);
  gather_kernel<<<2048, 256, 0, stream>>>(x, emb, idx, x_up, emb_up);
}

// Round 3
// 408.518 us; speedup vs baseline: 1.4023x; 1.1952x over previous
//
#include <hip/hip_runtime.h>

// LengthAdaptor: B=16, T=512, C_IN=512, C_HID=256, C_EMB=384, K=5, MAX_DUR=8
// Outputs (concat, f32): x_up [16,4096,512] | ldp [16,512] | emb_up [16,4096,384]
//
// Convs = bf16 MFMA implicit GEMM, hi/lo split precision.
// R3: B pre-swizzled into MFMA-fragment-contiguous layout (coalesced 1KB wave
// loads), Mtile=128 (halves B traffic), Ksplit=4 (occupancy 4 waves/SIMD),
// conv2 input pure-bf16 (2 MFMAs/frag instead of 3).

constexpr int Bn = 16, Tn = 512, CIN1 = 512, CHID = 256, CEMB = 384, MAXMEL = 4096;
constexpr int NROWS = Bn * Tn;  // 8192 GEMM rows
#define LRELU 0.3f
#define EPSV 1e-5f

typedef __attribute__((ext_vector_type(8))) short bf16x8;
typedef __attribute__((ext_vector_type(4))) float f32x4;
typedef unsigned short ushort_t;

static __device__ __forceinline__ ushort_t f2bf(float f) {
  unsigned u = __builtin_bit_cast(unsigned, f);
  unsigned r = (u + 0x7fffu + ((u >> 16) & 1u)) >> 16;  // RNE
  return (ushort_t)r;
}
static __device__ __forceinline__ float bf2f(ushort_t h) {
  unsigned u = ((unsigned)h) << 16;
  return __builtin_bit_cast(float, u);
}

// ---------------------------------------------------------------------------
// Weight prep: w [5][CI][256] f32 -> fragment-contiguous bf16 hi/lo.
// Fragment fr = (ksh*(CI/32) + ci32)*16 + cob holds 64 lanes x 8 ushorts:
//   frag[l][j] = W[ksh][ci32*32 + (l>>4)*8 + j][cob*16 + (l&15)]
// ---------------------------------------------------------------------------
__global__ __launch_bounds__(256) void wprep_kernel(const float* __restrict__ w,
                                                    ushort_t* __restrict__ hi,
                                                    ushort_t* __restrict__ lo,
                                                    int CI) {
  const int gid = blockIdx.x * 256 + threadIdx.x;    // coalesced source read
  const int ksh = gid / (CI * 256);
  const int rem = gid - ksh * CI * 256;
  const int ci = rem >> 8, co = rem & 255;
  const float v = w[gid];
  const ushort_t h = f2bf(v);
  const int ci32 = ci >> 5, cob = co >> 4;
  const int l = ((ci >> 3) & 3) * 16 + (co & 15);
  const int j = ci & 7;
  const size_t dst = ((size_t)((ksh * (CI / 32) + ci32) * 16 + cob)) * 512 + l * 8 + j;
  hi[dst] = h;
  lo[dst] = f2bf(v - bf2f(h));
}

// ---------------------------------------------------------------------------
// Conv MFMA kernel. grid (mt=64, ns=2, ks=4), block 512 = 8 waves (4mh x 2nh).
// Block tile 128 rows x 128 cols; wave tile 32x64 (2 im x 4 jn, acc 32 VGPR).
// A staged in LDS (stride 72 ushorts: bank-aligned 4-bank groups, conflict-min).
// B: coalesced fragment loads from pre-swizzled weights (L2-resident).
// Partials (no bias) -> part[ks][8192][256] f32.
// ---------------------------------------------------------------------------
template <int CI, bool F32IN>
__global__ __launch_bounds__(512, 4) void conv_mfma_kernel(
    const float* __restrict__ xin,        // F32IN: [8192][CI] f32
    const ushort_t* __restrict__ inhi,    // !F32IN: [8192][CI] bf16
    const ushort_t* __restrict__ wBhi,    // fragment-contiguous
    const ushort_t* __restrict__ wBlo,
    float* __restrict__ part) {           // [4][8192][256]
  constexpr int CIQ = CI / 4;             // K-split quarter (128 or 64)
  constexpr int NCHUNK = CIQ / 64;        // 2 or 1
  constexpr int ROWS = 132, LDSTRIDE = 72;
  __shared__ ushort_t sAhi[ROWS * LDSTRIDE];
  __shared__ ushort_t sAlo[F32IN ? ROWS * LDSTRIDE : 1];

  const int mt = blockIdx.x, ns = blockIdx.y, ks = blockIdx.z;
  const int b = mt >> 2, t0 = (mt & 3) * 128;
  const int tid = threadIdx.x;
  const int l = tid & 63, w = tid >> 6;
  const int mh = w >> 1, nh = w & 1;
  const int lm = l & 15, lq = l >> 4;

  f32x4 acc[2][4];
#pragma unroll
  for (int im = 0; im < 2; ++im)
#pragma unroll
    for (int jn = 0; jn < 4; ++jn) acc[im][jn] = (f32x4){0.f, 0.f, 0.f, 0.f};

  const ushort_t* pBh = wBhi + l * 8;     // + fr*512 per fragment
  const ushort_t* pBl = wBlo + l * 8;
  const int cobBase = ns * 8 + nh * 4;    // fragment col-block base
  const int rowBase = mh * 32 + lm;       // A: m = lane&15 (+ im*16 + ksh)

#pragma unroll 1
  for (int chunk = 0; chunk < NCHUNK; ++chunk) {
    // ---- stage ROWS x 64ci of A into LDS (packed uint writes) ----
    {
      const int cibase = ks * CIQ + chunk * 64;
#pragma unroll 1
      for (int i = 0; i < 9; ++i) {               // 9*512 >= 4224 pairs
        const int p = i * 512 + tid;
        if (p < ROWS * 32) {
          const int r = p >> 5, c2 = (p & 31) * 2;
          const int t = t0 - 2 + r;
          unsigned hv = 0, lv = 0;
          if ((unsigned)t < (unsigned)Tn) {
            const size_t src = (size_t)(b * Tn + t) * CI + cibase + c2;
            if (F32IN) {
              const float2 v = *(const float2*)(xin + src);
              const ushort_t h0 = f2bf(v.x), h1 = f2bf(v.y);
              hv = (unsigned)h0 | ((unsigned)h1 << 16);
              lv = (unsigned)f2bf(v.x - bf2f(h0)) |
                   ((unsigned)f2bf(v.y - bf2f(h1)) << 16);
            } else {
              hv = *(const unsigned*)(inhi + src);
            }
          }
          *(unsigned*)&sAhi[r * LDSTRIDE + c2] = hv;
          if (F32IN) *(unsigned*)&sAlo[r * LDSTRIDE + c2] = lv;
        }
      }
    }
    __syncthreads();

#pragma unroll 1
    for (int ksh = 0; ksh < 5; ++ksh) {
#pragma unroll
      for (int kk = 0; kk < 2; ++kk) {
        bf16x8 a_h[2], a_l[2];
#pragma unroll
        for (int im = 0; im < 2; ++im) {
          const int ad = (rowBase + im * 16 + ksh) * LDSTRIDE + kk * 32 + lq * 8;
          a_h[im] = *(const bf16x8*)&sAhi[ad];
          if (F32IN) a_l[im] = *(const bf16x8*)&sAlo[ad];
        }
        const int ci32 = ks * (CIQ / 32) + chunk * 2 + kk;
        const int frBase = (ksh * (CI / 32) + ci32) * 16 + cobBase;
#pragma unroll
        for (int jn = 0; jn < 4; ++jn) {
          const size_t fo = (size_t)(frBase + jn) * 512;
          const bf16x8 bh = *(const bf16x8*)(pBh + fo);
          const bf16x8 bl = *(const bf16x8*)(pBl + fo);
#pragma unroll
          for (int im = 0; im < 2; ++im) {
            acc[im][jn] = __builtin_amdgcn_mfma_f32_16x16x32_bf16(a_h[im], bh, acc[im][jn], 0, 0, 0);
            if (F32IN)
              acc[im][jn] = __builtin_amdgcn_mfma_f32_16x16x32_bf16(a_l[im], bh, acc[im][jn], 0, 0, 0);
            acc[im][jn] = __builtin_amdgcn_mfma_f32_16x16x32_bf16(a_h[im], bl, acc[im][jn], 0, 0, 0);
          }
        }
      }
    }
    __syncthreads();
  }

  // ---- write partials; D layout: col = lane&15, row = (lane>>4)*4 + reg ----
  float* pOut = part + (size_t)ks * NROWS * 256;
#pragma unroll
  for (int im = 0; im < 2; ++im)
#pragma unroll
    for (int jn = 0; jn < 4; ++jn) {
      const int col = ns * 128 + nh * 64 + jn * 16 + lm;
#pragma unroll
      for (int reg = 0; reg < 4; ++reg) {
        const int grow = b * Tn + t0 + mh * 32 + im * 16 + lq * 4 + reg;
        pOut[(size_t)grow * 256 + col] = acc[im][jn][reg];
      }
    }
}

// ---------------------------------------------------------------------------
// Reduce 4-way Ksplit + bias + leaky-relu + LayerNorm. One wave per row.
// FINAL=false: emit h1 bf16. FINAL=true: fused linear(256->1) + mask -> ldp.
// ---------------------------------------------------------------------------
template <bool FINAL>
__global__ __launch_bounds__(256) void ln_kernel(
    const float* __restrict__ part,       // [4][8192][256]
    const float* __restrict__ bias, const float* __restrict__ g,
    const float* __restrict__ be, ushort_t* __restrict__ h1,
    const float* __restrict__ lw, const float* __restrict__ lb,
    const unsigned char* __restrict__ mask, float* __restrict__ ldp) {
  const int row = blockIdx.x * 4 + (threadIdx.x >> 6);
  const int l = threadIdx.x & 63;
  const float4 bi = ((const float4*)bias)[l];
  float v0 = bi.x, v1 = bi.y, v2 = bi.z, v3 = bi.w;
#pragma unroll
  for (int k = 0; k < 4; ++k) {
    const float4 p = ((const float4*)(part + (size_t)k * NROWS * 256))[row * 64 + l];
    v0 += p.x; v1 += p.y; v2 += p.z; v3 += p.w;
  }
  v0 = (v0 > 0.f) ? v0 : LRELU * v0;
  v1 = (v1 > 0.f) ? v1 : LRELU * v1;
  v2 = (v2 > 0.f) ? v2 : LRELU * v2;
  v3 = (v3 > 0.f) ? v3 : LRELU * v3;
  float s = v0 + v1 + v2 + v3;
  float s2 = v0 * v0 + v1 * v1 + v2 * v2 + v3 * v3;
#pragma unroll
  for (int off = 32; off >= 1; off >>= 1) {
    s += __shfl_xor(s, off);
    s2 += __shfl_xor(s2, off);
  }
  const float mu = s * (1.f / 256.f);
  const float var = s2 * (1.f / 256.f) - mu * mu;
  const float rs = rsqrtf(var + EPSV);
  const float4 gg = ((const float4*)g)[l];
  const float4 bb = ((const float4*)be)[l];
  const float h0 = (v0 - mu) * rs * gg.x + bb.x;
  const float h1v = (v1 - mu) * rs * gg.y + bb.y;
  const float h2 = (v2 - mu) * rs * gg.z + bb.z;
  const float h3 = (v3 - mu) * rs * gg.w + bb.w;
  if (!FINAL) {
    ushort4 uh;
    uh.x = f2bf(h0); uh.y = f2bf(h1v); uh.z = f2bf(h2); uh.w = f2bf(h3);
    ((ushort4*)h1)[row * 64 + l] = uh;
  } else {
    const float4 lv = ((const float4*)lw)[l];
    float d = h0 * lv.x + h1v * lv.y + h2 * lv.z + h3 * lv.w;
#pragma unroll
    for (int off = 32; off >= 1; off >>= 1) d += __shfl_xor(d, off);
    if (l == 0) {
      float val = d + lb[0];
      if (mask[row]) val = 0.f;
      ldp[row] = val;
    }
  }
}

// ---------------------------------------------------------------------------
// Length regulation
// ---------------------------------------------------------------------------
__global__ __launch_bounds__(512) void build_idx_kernel(const int* __restrict__ dur,
                                                        int* __restrict__ idx) {
  __shared__ int cum[Tn];
  const int b = blockIdx.x, t = threadIdx.x;
  const int d = dur[b * Tn + t];
  cum[t] = d;
  __syncthreads();
  for (int off = 1; off < Tn; off <<= 1) {
    int v = (t >= off) ? cum[t - off] : 0;
    __syncthreads();
    cum[t] += v;
    __syncthreads();
  }
  const int end = cum[t];
  for (int p = end - d; p < end; ++p) idx[b * MAXMEL + p] = t;
  const int total = cum[Tn - 1];
  for (int p = total + t; p < MAXMEL; p += Tn) idx[b * MAXMEL + p] = -1;
}

__global__ __launch_bounds__(256) void gather_kernel(const float* __restrict__ x,
                                                     const float* __restrict__ emb,
                                                     const int* __restrict__ idx,
                                                     float* __restrict__ x_up,
                                                     float* __restrict__ emb_up) {
  const float4* x4 = (const float4*)x;
  const float4* e4 = (const float4*)emb;
  float4* xu4 = (float4*)x_up;
  float4* eu4 = (float4*)emb_up;
  const int tid0 = blockIdx.x * 256 + threadIdx.x;
  const int stride = gridDim.x * 256;
  const float4 z = make_float4(0.f, 0.f, 0.f, 0.f);
  for (int u = tid0; u < Bn * MAXMEL * 128; u += stride) {
    const int bp = u >> 7, i = u & 127;
    const int t = idx[bp];
    const int b = bp >> 12;
    xu4[u] = (t >= 0) ? x4[((b << 9) + t) * 128 + i] : z;
  }
  for (int u = tid0; u < Bn * MAXMEL * 96; u += stride) {
    const int bp = u / 96, i = u - bp * 96;
    const int t = idx[bp];
    const int b = bp >> 12;
    eu4[u] = (t >= 0) ? e4[((b << 9) + t) * 96 + i] : z;
  }
}

// ---------------------------------------------------------------------------
extern "C" void kernel_launch(void* const* d_in, const int* in_sizes, int n_in,
                              void* d_out, int out_size, void* d_ws, size_t ws_size,
                              hipStream_t stream) {
  const float* x     = (const float*)d_in[0];
  const float* x_res = (const float*)d_in[1];
  const int*   dur   = (const int*)d_in[2];
  const float* emb   = (const float*)d_in[3];
  const unsigned char* mask = (const unsigned char*)d_in[4];
  const float* c1w = (const float*)d_in[5];
  const float* c1b = (const float*)d_in[6];
  const float* g1  = (const float*)d_in[7];
  const float* b1  = (const float*)d_in[8];
  const float* c2w = (const float*)d_in[9];
  const float* c2b = (const float*)d_in[10];
  const float* g2  = (const float*)d_in[11];
  const float* b2  = (const float*)d_in[12];
  const float* lw  = (const float*)d_in[13];
  const float* lb  = (const float*)d_in[14];

  float* x_up   = (float*)d_out;
  float* ldp    = x_up + (size_t)Bn * MAXMEL * CIN1;
  float* emb_up = ldp + (size_t)Bn * Tn;

  // Scratch inside emb_up region (100.7 MB) — overwritten last by gather.
  float* part = emb_up;                                   // 4 x 8 MB
  ushort_t* w1hi = (ushort_t*)(part + (size_t)4 * NROWS * 256);
  ushort_t* w1lo = w1hi + (size_t)5 * 512 * 256;
  ushort_t* w2hi = w1lo + (size_t)5 * 512 * 256;
  ushort_t* w2lo = w2hi + (size_t)5 * 256 * 256;

  // ws: idx (256 KB) + h1 bf16 (4 MB)
  int* idx = (int*)d_ws;
  ushort_t* h1 = (ushort_t*)((char*)d_ws + (size_t)Bn * MAXMEL * sizeof(int));

  wprep_kernel<<<5 * 512 * 256 / 256, 256, 0, stream>>>(c1w, w1hi, w1lo, 512);
  wprep_kernel<<<5 * 256 * 256 / 256, 256, 0, stream>>>(c2w, w2hi, w2lo, 256);
  conv_mfma_kernel<512, true><<<dim3(64, 2, 4), 512, 0, stream>>>(
      x_res, nullptr, w1hi, w1lo, part);
  ln_kernel<false><<<NROWS / 4, 256, 0, stream>>>(
      part, c1b, g1, b1, h1, nullptr, nullptr, nullptr, nullptr);
  conv_mfma_kernel<256, false><<<dim3(64, 2, 4), 512, 0, stream>>>(
      nullptr, h1, w2hi, w2lo, part);
  ln_kernel<true><<<NROWS / 4, 256, 0, stream>>>(
      part, c2b, g2, b2, nullptr, lw, lb, mask, ldp);
  build_idx_kernel<<<Bn, Tn, 0, stream>>>(dur, idx);
  gather_kernel<<<2048, 256, 0, stream>>>(x, emb, idx, x_up, emb_up);
}